// Round 7
// baseline (1197.600 us; speedup 1.0000x reference)
//
#include <hip/hip_runtime.h>
#include <cstdint>
#include <cstddef>

#define P_TOT 114688   // N*H*W = 4*128*224
#define W_IMG 224
#define H_IMG 128
#define WP 228         // padded row width (1 left, 3 right)
#define HP 130         // padded rows (1 top, 1 bottom)
#define IMG_PX (HP * WP)        // 29640
#define VALID_PX (128 * WP)     // 29184 = 114*256 contiguous px covering rows 1..128
#define NBLK_IMG (VALID_PX / 256)  // 114

typedef _Float16 f16;
typedef __attribute__((ext_vector_type(8))) _Float16 f16x8;
typedef __attribute__((ext_vector_type(4))) _Float16 f16x4;
typedef __attribute__((ext_vector_type(4))) float f32x4;

#define WAITVM(N) asm volatile("s_waitcnt vmcnt(" #N ")" ::: "memory")

__device__ __forceinline__ void barrier_sync() {
  asm volatile("" ::: "memory");
  __builtin_amdgcn_s_barrier();
  asm volatile("" ::: "memory");
}

__device__ __forceinline__ void gload16(const void* g, void* l) {
  __builtin_amdgcn_global_load_lds((const __attribute__((address_space(1))) void*)g,
                                   (__attribute__((address_space(3))) void*)l, 16, 0, 0);
}

__device__ __forceinline__ size_t pad_px(int n, int h, int w) {
  return ((size_t)(n * HP + h + 1)) * WP + (w + 1);
}

// ---------------- zero the halo pixels of a padded slab --------------------------
__global__ void k_halo(f16* __restrict__ slab, int CS) {
  int c8n = CS >> 3;
  int tid = blockIdx.x * 256 + threadIdx.x;
  int c8 = tid % c8n;
  int rest = tid / c8n;
  if (rest >= 4 * 968) return;
  int n = rest / 968, i = rest % 968;
  int h, w;
  if (i < 456) { h = (i < 228) ? 0 : 129; w = i % 228; }
  else { int j = i - 456; h = 1 + (j >> 2); int k = j & 3; w = (k == 0) ? 0 : (224 + k); }
  size_t pp = ((size_t)(n * HP + h)) * WP + w;
  *(f16x8*)(slab + pp * CS + c8 * 8) = (f16x8){0, 0, 0, 0, 0, 0, 0, 0};
}

// ---------------- pack input: fp32 NCHW -> fp16 padded-NHWC, chunk-swizzled ------
// stored slot = true_chunk ^ ((pp>>1)&3) within each 32-ch group (pp = padded linear px)
__global__ void k_pack_x(const float* __restrict__ x, f16* __restrict__ xb) {
  int tid = threadIdx.x;
  int pw  = tid & 15;
  int c8  = tid >> 4;                 // 0..31
  int p   = blockIdx.x * 16 + pw;     // grid = P_TOT/16
  int w   = p % W_IMG;
  int h   = (p / W_IMG) % H_IMG;
  int n   = p / (H_IMG * W_IMG);
  const float* src = x + ((size_t)(n * 256 + c8 * 8) * H_IMG + h) * W_IMG + w;
  f16x8 v;
#pragma unroll
  for (int j = 0; j < 8; j++) v[j] = (f16)src[(size_t)j * (H_IMG * W_IMG)];
  size_t pp = pad_px(n, h, w);
  int c8s = (c8 & ~3) | ((c8 ^ (int)(pp >> 1)) & 3);
  *(f16x8*)(xb + pp * 256 + c8s * 8) = v;
}

// ---------------- pack weights into [q][OT][32] (q = kk*CC+c), swizzled by o -----
__global__ void k_pack_w(const float* __restrict__ wa, const float* __restrict__ wb,
                         f16* __restrict__ dst, int mode, int OT, int CS,
                         int Coh, int Cih, int total) {
  int gid = blockIdx.x * 256 + threadIdx.x;
  if (gid >= total) return;
  int j  = gid & 31;
  int t1 = gid >> 5;
  int o  = t1 % OT;
  int t2 = t1 / OT;
  int CCc = CS >> 5;
  int cc = t2 % CCc;
  int kk = t2 / CCc;
  int chunkT = ((j >> 3) ^ (o >> 1)) & 3;   // stored slot holds true chunk slot^key
  int is = cc * 32 + chunkT * 8 + (j & 7);
  float val = 0.f;
  if (mode == 0) {
    val = (o < Coh) ? wa[((size_t)o * Cih + is) * 9 + kk]
                    : wb[((size_t)(o - Coh) * Cih + is) * 9 + kk];
  } else if (mode == 1) {
    if (o < Coh) {
      val = (is < Cih) ? wa[((size_t)o * Cih + is) * 9 + kk]
                       : -wb[((size_t)o * Cih + (is - Cih)) * 9 + kk];
    } else {
      int oo = o - Coh;
      val = (is < Cih) ? wb[((size_t)oo * Cih + is) * 9 + kk]
                       : wa[((size_t)oo * Cih + (is - Cih)) * 9 + kk];
    }
  } else {
    if (o == 0)      val = wa[(size_t)is * 9 + kk];
    else if (o == 1) val = wb[(size_t)is * 9 + kk];
    else if (o == 2) val = wb[(size_t)(96 + is) * 9 + kk];
  }
  dst[gid] = (f16)val;
}

// ---------------- implicit-GEMM conv: 256-px tiles, 8 waves, acc=48 -------------
template<int OT, int CS, bool HEAD>
__launch_bounds__(HEAD ? 128 : 512)
__global__ void k_gemm(const f16* __restrict__ xb, const f16* __restrict__ Apack,
                       f16* __restrict__ y, float* __restrict__ outh,
                       const float* __restrict__ bcp, const float* __restrict__ bgp,
                       float* __restrict__ sums, float* __restrict__ sumsq) {
  constexpr int BM  = HEAD ? 16 : 96;
  constexpr int BN  = HEAD ? 224 : 256;
  constexpr int WM  = HEAD ? 1 : 2;
  constexpr int WN  = HEAD ? 2 : 4;
  constexpr int NWV = WM * WN;
  constexpr int CC  = CS / 32;
  constexpr int NCH = 9 * CC;
  constexpr int MF  = BM / (WM * 16);      // 3 / 1
  constexpr int NF  = BN / (WN * 16);      // 4 / 7
  constexpr int ACH = BM / 16;             // 6 / 1
  constexpr int APAD = HEAD ? ACH : 8;     // A region chunks (padded to keep loads uniform)
  constexpr int BCH = BN / 16;             // 16 / 14
  constexpr int TCH = APAD + BCH;          // 24 / 15
  constexpr int LDSB = TCH * 1024;
  __shared__ __align__(16) char lds[2][LDSB];

  constexpr int NOT = OT / BM;
  constexpr int nwg = HEAD ? 512 : NOT * 4 * NBLK_IMG;
  const int bid = blockIdx.x;
  const int swz = (bid & 7) * (nwg >> 3) + (bid >> 3);  // XCD swizzle (nwg%8==0)

  int ot, n, h;
  size_t PB;   // global padded pixel index of tile's first pixel
  if constexpr (HEAD) {
    ot = 0;
    n = swz >> 7; h = swz & 127;
    PB = pad_px(n, h, 0);
  } else {
    ot = swz % NOT;
    int r = swz / NOT;
    n = r / NBLK_IMG;
    int blk = r % NBLK_IMG;
    PB = (size_t)n * IMG_PX + WP + blk * 256;
    h = 0;
  }

  const int tid  = threadIdx.x;
  const int lane = tid & 63;
  const int wv   = tid >> 6;
  const int wm   = wv % WM;
  const int wn   = wv / WM;
  const int obase  = wm * (MF * 16);
  const int wnbase = wn * (NF * 16);
  const int l15 = lane & 15;
  const int lhi = lane >> 4;
  const int aoff = l15 * 64 + (((lhi ^ (l15 >> 1)) & 3) << 4);
  const int pblb = (int)PB;   // low bits of PB for swizzle keys

  f32x4 acc[MF][NF];
#pragma unroll
  for (int mi = 0; mi < MF; mi++)
#pragma unroll
    for (int ni = 0; ni < NF; ni++) acc[mi][ni] = (f32x4){0.f, 0.f, 0.f, 0.f};

  // hoisted per-thread staging bases (branch-free: halo pre-zeroed; OOB reads land
  // in-workspace and only feed masked/re-zeroed halo outputs)
  const char* abase = (const char*)Apack + (size_t)ot * BM * 64 + lane * 16;
  const char* bbase = (const char*)xb + (PB + (lane >> 2)) * (size_t)(CS * 2) + (lane & 3) * 16;

  auto stage1 = [&](char* base, int q) {
    const int kk = q / CC, c = q % CC;
    const int doff = (kk / 3 - 1) * WP + (kk % 3 - 1);
    const char* asrc = abase + (size_t)q * (OT * 64);
    const char* bsrc = bbase + doff * (CS * 2) + c * 64;
    if constexpr (!HEAD) {
#pragma unroll
      for (int i = 0; i < TCH / NWV; i++) {
        int ck = wv + i * NWV;
        char* dst = base + ck * 1024;
        const char* src = (ck < APAD) ? (asrc + ck * 1024)
                                      : (bsrc + (ck - APAD) * (16 * CS * 2));
        gload16(src, dst);
      }
    } else {
      for (int ck = wv; ck < TCH; ck += NWV) {
        char* dst = base + ck * 1024;
        const char* src = (ck < APAD) ? (asrc + ck * 1024)
                                      : (bsrc + (ck - APAD) * (16 * CS * 2));
        gload16(src, dst);
      }
    }
  };

  auto compute_half = [&](const char* base, int q) {
    const int kk = q / CC;
    const int pbl = pblb + (kk / 3 - 1) * WP + (kk % 3 - 1);
    const char* Ab = base;
    const char* Bb = base + APAD * 1024;
    f16x8 af[MF], bfr[NF];
#pragma unroll
    for (int mi = 0; mi < MF; mi++)
      af[mi] = *(const f16x8*)(Ab + (obase + mi * 16) * 64 + aoff);
#pragma unroll
    for (int ni = 0; ni < NF; ni++) {
      int px = wnbase + ni * 16 + l15;
      int sw = ((lhi ^ ((pbl + px) >> 1)) & 3) << 4;
      bfr[ni] = *(const f16x8*)(Bb + px * 64 + sw);
    }
    __builtin_amdgcn_s_setprio(1);
#pragma unroll
    for (int mi = 0; mi < MF; mi++)
#pragma unroll
      for (int ni = 0; ni < NF; ni++)
        acc[mi][ni] = __builtin_amdgcn_mfma_f32_16x16x32_f16(af[mi], bfr[ni], acc[mi][ni], 0, 0, 0);
    __builtin_amdgcn_s_setprio(0);
  };

  if constexpr (!HEAD) {
    stage1((char*)&lds[0][0], 0);
    int buf = 0;
    for (int t = 0; t < NCH; ++t) {
      if (t + 1 < NCH) { stage1((char*)&lds[buf ^ 1][0], t + 1); WAITVM(3); }
      else             { WAITVM(0); }
      barrier_sync();
      compute_half((const char*)&lds[buf][0], t);
      barrier_sync();
      buf ^= 1;
    }
  } else {
    stage1((char*)&lds[0][0], 0);
    __syncthreads();
    int buf = 0;
    for (int t = 0; t < NCH; ++t) {
      if (t + 1 < NCH) stage1((char*)&lds[buf ^ 1][0], t + 1);
      compute_half((const char*)&lds[buf][0], t);
      __syncthreads();
      buf ^= 1;
    }
  }

  if constexpr (!HEAD) {
    // store fp16 padded-NHWC output (linear channel order; halo px garbage -> k_halo)
#pragma unroll
    for (int mi = 0; mi < MF; mi++) {
#pragma unroll
      for (int ni = 0; ni < NF; ni++) {
        int o = obase + mi * 16 + lhi * 4;
        int px = wnbase + ni * 16 + l15;
        f16x4 v4;
#pragma unroll
        for (int j = 0; j < 4; j++) v4[j] = (f16)acc[mi][ni][j];
        *(f16x4*)(y + (PB + px) * OT + ot * BM + o) = v4;
      }
    }
    // fused BN stats (mask out col-halo pixels)
    float msk[NF];
#pragma unroll
    for (int ni = 0; ni < NF; ni++) {
      int wcol = (int)((PB + (size_t)(wnbase + ni * 16 + l15)) % (size_t)WP);
      msk[ni] = (wcol >= 1 && wcol <= 224) ? 1.f : 0.f;
    }
    float sv[MF][4], qv[MF][4];
#pragma unroll
    for (int mi = 0; mi < MF; mi++)
#pragma unroll
      for (int j = 0; j < 4; j++) {
        float s = 0.f, q = 0.f;
#pragma unroll
        for (int ni = 0; ni < NF; ni++) {
          float v = acc[mi][ni][j] * msk[ni];
          s += v; q += v * acc[mi][ni][j];
        }
        sv[mi][j] = s; qv[mi][j] = q;
      }
#pragma unroll
    for (int m = 1; m < 16; m <<= 1) {
#pragma unroll
      for (int mi = 0; mi < MF; mi++)
#pragma unroll
        for (int j = 0; j < 4; j++) {
          sv[mi][j] += __shfl_xor(sv[mi][j], m);
          qv[mi][j] += __shfl_xor(qv[mi][j], m);
        }
    }
    if (l15 == 0) {
#pragma unroll
      for (int mi = 0; mi < MF; mi++)
#pragma unroll
        for (int j = 0; j < 4; j++) {
          int ch = ot * BM + obase + mi * 16 + lhi * 4 + j;
          atomicAdd(&sums[ch], sv[mi][j]);
          atomicAdd(&sumsq[ch], qv[mi][j]);
        }
    }
  } else {
    if (lhi == 0) {
      float b0 = bcp[0], b1 = bgp[0], b2 = bgp[1];
#pragma unroll
      for (int ni = 0; ni < NF; ni++) {
        int w = wnbase + ni * 16 + l15;
        float c0 = acc[0][ni][0] + b0;
        c0 = 1.f / (1.f + expf(-c0));
        float c1 = acc[0][ni][1] + b1;
        float c2 = acc[0][ni][2] + b2;
        outh[((size_t)(n * 3 + 0) * H_IMG + h) * W_IMG + w] = c0;
        outh[((size_t)(n * 3 + 1) * H_IMG + h) * W_IMG + w] = c1;
        outh[((size_t)(n * 3 + 2) * H_IMG + h) * W_IMG + w] = c2;
      }
    }
  }
}

// ---------------- BN coefficient recompute (fused into consumers) ---------------
template<int O>
__device__ __forceinline__ void bn_coef(const float* __restrict__ sums,
                                        const float* __restrict__ sumsq,
                                        const float* __restrict__ g,
                                        const float* __restrict__ b,
                                        float* sc, float* sh, int tid, int nt) {
  const float inv = 1.0f / (float)P_TOT;
  for (int t = tid; t < O; t += nt) {
    float mean = sums[t] * inv;
    float var  = fmaxf(sumsq[t] * inv - mean * mean, 0.f);
    int gi = (t < O / 2) ? t : (t - O / 2);
    float s = g[gi] * rsqrtf(var + 1e-5f);
    sc[t] = s;
    sh[t] = b[gi] - mean * s;
  }
}

// ---------------- in-place BN + ReLU + chunk-swizzle (pp-keyed) -----------------
template<int O>
__global__ void k_packip(f16* __restrict__ y,
                         const float* __restrict__ sums, const float* __restrict__ sumsq,
                         const float* __restrict__ g, const float* __restrict__ b) {
  __shared__ float sc[O], sh[O];
  bn_coef<O>(sums, sumsq, g, b, sc, sh, threadIdx.x, 256);
  __syncthreads();
  constexpr int G32 = O / 32;
  int gid = blockIdx.x * 256 + threadIdx.x;
  if (gid >= P_TOT * G32) return;
  int gg = gid % G32;
  int p = gid / G32;
  int w = p % W_IMG;
  int hh = (p / W_IMG) % H_IMG;
  int nn = p / (W_IMG * H_IMG);
  size_t pp = pad_px(nn, hh, w);
  f16* base = y + pp * O + gg * 32;
  f16x8 in[4];
#pragma unroll
  for (int ch = 0; ch < 4; ch++) in[ch] = *(const f16x8*)(base + ch * 8);
  int sw = (int)(pp >> 1) & 3;
  f16x8 outv[4];
#pragma unroll
  for (int ch = 0; ch < 4; ch++) {
#pragma unroll
    for (int j = 0; j < 8; j++) {
      int cdx = gg * 32 + ch * 8 + j;
      float f = fmaxf(fmaf((float)in[ch][j], sc[cdx], sh[cdx]), 0.f);
      outv[ch][j] = (f16)f;
    }
  }
#pragma unroll
  for (int ch = 0; ch < 4; ch++) *(f16x8*)(base + ((ch ^ sw) & 3) * 8) = outv[ch];
}

// ---------------- BN(L4) + ReLU + complex magnitude -> 96ch swizzled ------------
__global__ void k_mag(const f16* __restrict__ y,
                      const float* __restrict__ sums, const float* __restrict__ sumsq,
                      const float* __restrict__ g, const float* __restrict__ b,
                      f16* __restrict__ mg) {
  __shared__ float sc[192], sh[192];
  bn_coef<192>(sums, sumsq, g, b, sc, sh, threadIdx.x, 256);
  __syncthreads();
  int gid = blockIdx.x * 256 + threadIdx.x;
  if (gid >= P_TOT * 12) return;
  int c8 = gid % 12;
  int p  = gid / 12;
  int w  = p % W_IMG;
  int hh = (p / W_IMG) % H_IMG;
  int nn = p / (W_IMG * H_IMG);
  size_t pp = pad_px(nn, hh, w);
  f16x8 r8 = *(const f16x8*)(y + pp * 192 + c8 * 8);
  f16x8 i8 = *(const f16x8*)(y + pp * 192 + 96 + c8 * 8);
  f16x8 outv;
#pragma unroll
  for (int j = 0; j < 8; j++) {
    int cdx = c8 * 8 + j;
    float rr = fmaxf(fmaf((float)r8[j], sc[cdx], sh[cdx]), 0.f);
    float ii = fmaxf(fmaf((float)i8[j], sc[96 + cdx], sh[96 + cdx]), 0.f);
    outv[j] = (f16)sqrtf(rr * rr + ii * ii);
  }
  int c8s = (c8 & ~3) | ((c8 ^ (int)(pp >> 1)) & 3);
  *(f16x8*)(mg + pp * 96 + c8s * 8) = outv;
}

// ------------------------------------------------------------------------------
extern "C" void kernel_launch(void* const* d_in, const int* in_sizes, int n_in,
                              void* d_out, int out_size, void* d_ws, size_t ws_size,
                              hipStream_t stream) {
  const float* x   = (const float*)d_in[0];
  const float* w1r = (const float*)d_in[1];
  const float* w1i = (const float*)d_in[2];
  const float* g1  = (const float*)d_in[3];
  const float* b1  = (const float*)d_in[4];
  const float* w2r = (const float*)d_in[5];
  const float* w2i = (const float*)d_in[6];
  const float* g2  = (const float*)d_in[7];
  const float* b2  = (const float*)d_in[8];
  const float* w3r = (const float*)d_in[9];
  const float* w3i = (const float*)d_in[10];
  const float* g3  = (const float*)d_in[11];
  const float* b3  = (const float*)d_in[12];
  const float* w4r = (const float*)d_in[13];
  const float* w4i = (const float*)d_in[14];
  const float* g4  = (const float*)d_in[15];
  const float* b4  = (const float*)d_in[16];
  const float* wc  = (const float*)d_in[17];
  const float* bcp = (const float*)d_in[18];
  const float* wg  = (const float*)d_in[19];
  const float* bgp = (const float*)d_in[20];
  float* out = (float*)d_out;

  char* ws = (char*)d_ws;
  if (ws_size < 137500000ULL) return;

  auto S  = [&](int L) { return (float*)(ws + 16384 + L * 4096); };
  auto Q  = [&](int L) { return (float*)(ws + 16384 + L * 4096) + 512; };
  f16* A1 = (f16*)(ws + 65536);        // 72*288*64 = 1,327,104 B (+8K pad)
  f16* A2 = (f16*)(ws + 1441792);      // 81*192*64 =   995,328 B (+8K pad)
  f16* A3 = (f16*)(ws + 2490368);      // 54*192*64 =   663,552 B (+8K pad)
  f16* A4 = (f16*)(ws + 3211264);      // same
  f16* AH = (f16*)(ws + 3932160);      // 27*16*64  =    27,648 B
  f16* SLA = (f16*)(ws + 5242880);     // padded slab, 119296 px * 256ch * 2B = 61.1MB
  f16* SLB = (f16*)(ws + 67108864);    // padded slab, 119296 px * 288ch * 2B = 68.7MB

  hipMemsetAsync(d_ws, 0, 49152, stream);  // stats sums

  auto halo_grid = [](int CS) { return (4 * 968 * (CS / 8) + 255) / 256; };

  k_halo<<<halo_grid(256), 256, 0, stream>>>(SLA, 256);
  k_pack_x<<<P_TOT / 16, 512, 0, stream>>>(x, SLA);
  k_pack_w<<<(663552 + 255) / 256, 256, 0, stream>>>(w1r, w1i, A1, 0, 288, 256, 144, 256, 663552);
  k_pack_w<<<(497664 + 255) / 256, 256, 0, stream>>>(w2r, w2i, A2, 1, 192, 288, 96, 144, 497664);
  k_pack_w<<<(331776 + 255) / 256, 256, 0, stream>>>(w3r, w3i, A3, 1, 192, 192, 96, 96, 331776);
  k_pack_w<<<(331776 + 255) / 256, 256, 0, stream>>>(w4r, w4i, A4, 1, 192, 192, 96, 96, 331776);
  k_pack_w<<<(13824 + 255) / 256, 256, 0, stream>>>(wc, wg, AH, 2, 16, 96, 0, 96, 13824);

  // L1: 256 -> 288
  k_gemm<288, 256, false><<<3 * 4 * NBLK_IMG, 512, 0, stream>>>(SLA, A1, SLB, nullptr, nullptr, nullptr, S(0), Q(0));
  k_packip<288><<<P_TOT * 9 / 256, 256, 0, stream>>>(SLB, S(0), Q(0), g1, b1);
  k_halo<<<halo_grid(288), 256, 0, stream>>>(SLB, 288);

  // L2: 288 -> 192
  k_gemm<192, 288, false><<<2 * 4 * NBLK_IMG, 512, 0, stream>>>(SLB, A2, SLA, nullptr, nullptr, nullptr, S(1), Q(1));
  k_packip<192><<<P_TOT * 6 / 256, 256, 0, stream>>>(SLA, S(1), Q(1), g2, b2);
  k_halo<<<halo_grid(192), 256, 0, stream>>>(SLA, 192);

  // L3: 192 -> 192
  k_gemm<192, 192, false><<<2 * 4 * NBLK_IMG, 512, 0, stream>>>(SLA, A3, SLB, nullptr, nullptr, nullptr, S(2), Q(2));
  k_packip<192><<<P_TOT * 6 / 256, 256, 0, stream>>>(SLB, S(2), Q(2), g3, b3);
  k_halo<<<halo_grid(192), 256, 0, stream>>>(SLB, 192);

  // L4: 192 -> 192
  k_gemm<192, 192, false><<<2 * 4 * NBLK_IMG, 512, 0, stream>>>(SLB, A4, SLA, nullptr, nullptr, nullptr, S(3), Q(3));

  // BN+ReLU+magnitude -> 96ch head input (valid px only; stats were halo-masked)
  k_mag<<<P_TOT * 12 / 256, 256, 0, stream>>>(SLA, S(3), Q(3), g4, b4, SLB);
  k_halo<<<halo_grid(96), 256, 0, stream>>>(SLB, 96);

  // head: 96 -> 3 (sigmoid on ch0), writes NCHW fp32 output
  k_gemm<16, 96, true><<<512, 128, 0, stream>>>(SLB, AH, nullptr, out, bcp, bgp, nullptr, nullptr);

  (void)in_sizes; (void)n_in; (void)out_size;
}